// Round 2
// baseline (300.518 us; speedup 1.0000x reference)
//
#include <hip/hip_runtime.h>
#include <hip/hip_bf16.h>
#include <stdint.h>

#define K_DIM 1024
#define N_DIM 1024
// fallback (fused f32) tile
#define BM 128
#define BN 128
#define BK 32
// 8-phase bf16 tile
#define TBM 256
#define TBN 256
#define TBK 64

typedef __attribute__((ext_vector_type(8))) short short8;
typedef __attribute__((ext_vector_type(4))) float f32x4;

// ---- async global->LDS, 16B per lane (dest = wave-uniform base + lane*16) ----
__device__ __forceinline__ void gld16(const void* g, void* l) {
    __builtin_amdgcn_global_load_lds(
        (const __attribute__((address_space(1))) uint32_t*)(uintptr_t)g,
        (__attribute__((address_space(3))) uint32_t*)(uint32_t)(uintptr_t)l,
        16, 0, 0);
}

// pack two fp32 -> bf16x2 (round-half-up; |rel err| <= 2^-9)
__device__ __forceinline__ uint32_t pack2(float lo, float hi) {
    uint32_t a = __float_as_uint(lo) + 0x8000u;
    uint32_t b = __float_as_uint(hi) + 0x8000u;
    return __builtin_amdgcn_perm(b, a, 0x07060302u);
}

// XCD-aware swizzle for the 128-tile fallback path
__device__ __forceinline__ void block_map(int b, int& mb, int& nb) {
    int xcd = b & 7;
    int i = b >> 3;
    mb = xcd * 32 + (i >> 3);
    nb = i & 7;
}

// ---- stage 1: per-block |W| partial sums (fp64, deterministic) ----
__global__ void k_abs_partial(const float* __restrict__ W, double* __restrict__ part, int n4) {
    int stride = gridDim.x * blockDim.x;
    double s = 0.0;
    for (int i = blockIdx.x * blockDim.x + threadIdx.x; i < n4; i += stride) {
        float4 v = ((const float4*)W)[i];
        s += (double)fabsf(v.x) + (double)fabsf(v.y) + (double)fabsf(v.z) + (double)fabsf(v.w);
    }
    for (int o = 32; o > 0; o >>= 1) s += __shfl_down(s, o, 64);
    __shared__ double sm[4];
    int lane = threadIdx.x & 63, wv = threadIdx.x >> 6;
    if (lane == 0) sm[wv] = s;
    __syncthreads();
    if (threadIdx.x == 0) part[blockIdx.x] = sm[0] + sm[1] + sm[2] + sm[3];
}

// ---- stage 2: final reduce, store threshold = 0.5*mean(|W|) at ws[0] ----
__global__ void k_abs_final(double* __restrict__ ws) {
    double s = ws[8 + threadIdx.x];
    for (int o = 32; o > 0; o >>= 1) s += __shfl_down(s, o, 64);
    __shared__ double sm[4];
    int lane = threadIdx.x & 63, wv = threadIdx.x >> 6;
    if (lane == 0) sm[wv] = s;
    __syncthreads();
    if (threadIdx.x == 0)
        ws[0] = 0.5 * (sm[0] + sm[1] + sm[2] + sm[3]) / (double)(K_DIM * N_DIM);
}

// ---- stage 3: ternary quantize W -> bf16 {-1,0,+1} ----
__global__ void k_quant(const float* __restrict__ W, const double* __restrict__ thr,
                        ushort* __restrict__ wt, int n4) {
    float t = (float)thr[0];
    int i = blockIdx.x * blockDim.x + threadIdx.x;
    if (i >= n4) return;
    float4 v = ((const float4*)W)[i];
    ushort4 o;
    o.x = v.x > t ? 0x3F80u : (v.x < -t ? 0xBF80u : 0u);
    o.y = v.y > t ? 0x3F80u : (v.y < -t ? 0xBF80u : 0u);
    o.z = v.z > t ? 0x3F80u : (v.z < -t ? 0xBF80u : 0u);
    o.w = v.w > t ? 0x3F80u : (v.w < -t ? 0xBF80u : 0u);
    ((ushort4*)wt)[i] = o;
}

// ================= fused-cvt 8-phase 256x256 GEMM =================
// A path: x fp32 -> regs (8x float4, T14 issue-early) -> pack bf16 -> ds_write
//         with XOR swizzle applied AT THE WRITE (both-sides swizzle, rule 21).
// B path: wt bf16 via global_load_lds, pre-swizzled global source, linear dest.
// LDS tile layout: [256 rows][64 bf16], 128B/row; byte ^= ((row&7)<<4).
// Counted vmcnt: per iter, pinned issue order [B(t+1) x4 gld16][A(t+2) x8 loads]
// -> vmcnt(8) at P4 drains B, keeps 8 A-loads in flight across the barrier.

__device__ __forceinline__ short8 ldfrag(const ushort* base, int row, int cb) {
    return *(const short8*)((const char*)base + (row << 7) + (cb ^ ((row & 7) << 4)));
}

__device__ __forceinline__ void rd_a(const ushort* base, int row0, int quad, short8 (&a)[4][2]) {
#pragma unroll
    for (int mi = 0; mi < 4; mi++) {
        const int row = row0 + mi * 16;
        a[mi][0] = ldfrag(base, row, (quad << 4));
        a[mi][1] = ldfrag(base, row, 64 + (quad << 4));
    }
}

template <int NH>
__device__ __forceinline__ void rd_b(const ushort* base, int row0, int quad, short8 (&bq)[4][2]) {
#pragma unroll
    for (int j = 0; j < 2; j++) {
        const int row = row0 + (NH * 2 + j) * 16;
        bq[NH * 2 + j][0] = ldfrag(base, row, (quad << 4));
        bq[NH * 2 + j][1] = ldfrag(base, row, 64 + (quad << 4));
    }
}

template <int MH, int NH>
__device__ __forceinline__ void mmq(const short8 (&a)[4][2], const short8 (&bq)[4][2],
                                    f32x4 (&acc)[8][4]) {
#pragma unroll
    for (int mi = 0; mi < 4; mi++)
#pragma unroll
        for (int j = 0; j < 2; j++) {
            acc[MH * 4 + mi][NH * 2 + j] = __builtin_amdgcn_mfma_f32_16x16x32_bf16(
                a[mi][0], bq[NH * 2 + j][0], acc[MH * 4 + mi][NH * 2 + j], 0, 0, 0);
            acc[MH * 4 + mi][NH * 2 + j] = __builtin_amdgcn_mfma_f32_16x16x32_bf16(
                a[mi][1], bq[NH * 2 + j][1], acc[MH * 4 + mi][NH * 2 + j], 0, 0, 0);
        }
}

#define VMCNT(n) asm volatile("s_waitcnt vmcnt(" #n ")" ::: "memory")
#define LGKM0()  asm volatile("s_waitcnt lgkmcnt(0)" ::: "memory")
#define BARX()   __builtin_amdgcn_s_barrier()
#define PRIO1()  __builtin_amdgcn_s_setprio(1)
#define PRIO0()  __builtin_amdgcn_s_setprio(0)
#define SCHED0() __builtin_amdgcn_sched_barrier(0)

__global__ __launch_bounds__(512, 2) void k_gemm_fused(
    const float* __restrict__ x, const ushort* __restrict__ wt,
    const float* __restrict__ bias, float* __restrict__ out) {
    __shared__ __align__(16) ushort As[2][TBM * TBK];   // 2 x 32 KB
    __shared__ __align__(16) ushort Bs[2][TBN * TBK];   // 2 x 32 KB

    const int tid  = threadIdx.x;
    const int lane = tid & 63;
    const int r    = lane & 15;
    const int quad = lane >> 4;
    const int wv   = tid >> 6;
    const int wm   = wv >> 2;      // 0..1 : 128-row half
    const int wn   = wv & 3;       // 0..3 : 64-col slice

    // bijective XCD swizzle (grid % 8 == 0); n fastest so 4 same-XCD blocks share A
    const int cpx  = gridDim.x >> 3;
    const int bswz = (blockIdx.x & 7) * cpx + (blockIdx.x >> 3);
    const int m0 = (bswz >> 2) * TBM;
    const int n0 = (bswz & 3) * TBN;

    // ---- B staging (gld16): thread -> (row = tid>>3, 16B chunk = tid&7), pre-swz src
    const int srow = tid >> 3;
    const int scol = ((tid & 7) ^ (srow & 7)) << 3;
    const ushort* gB = wt + (size_t)(n0 + srow) * K_DIM + scol;
    const int ldst = srow * TBK + ((tid & 7) << 3);
#define STG_B(d, kt, u) gld16(gB + (size_t)((u) * 64) * K_DIM + (kt) * TBK, &Bs[d][(u) * 64 * TBK + ldst])

    // ---- A staging (reg): thread covers rows (tid>>4)+32s, float4 col = tid&15
    const float* gAx = x + (size_t)(m0 + (tid >> 4)) * K_DIM + (tid & 15) * 4;
    // LDS write byte offset within a row (swizzled; row&7 == (tid>>4)&7 for all s)
    const int cA = ((tid & 15) * 8) ^ (((tid >> 4) & 7) << 4);
    float4 rx[8];

#define LOAD_A(kt)                                                              \
    {                                                                           \
        _Pragma("unroll") for (int s = 0; s < 8; s++)                           \
            rx[s] = *(const float4*)(gAx + (size_t)(s * 32) * K_DIM + (kt) * TBK); \
    }
#define PACK_A(d)                                                               \
    {                                                                           \
        char* ab = (char*)As[d];                                                \
        _Pragma("unroll") for (int s = 0; s < 8; s++) {                         \
            uint2 w;                                                            \
            w.x = pack2(rx[s].x, rx[s].y);                                      \
            w.y = pack2(rx[s].z, rx[s].w);                                      \
            *(uint2*)(ab + (((tid >> 4) + 32 * s) << 7) + cA) = w;              \
        }                                                                       \
    }

    f32x4 acc[8][4];
#pragma unroll
    for (int i = 0; i < 8; i++)
#pragma unroll
        for (int j = 0; j < 4; j++) acc[i][j] = (f32x4){0.f, 0.f, 0.f, 0.f};

    short8 a[4][2], bq[4][2];
    const int ra0 = wm * 128 + r;
    const int rb0 = wn * 64 + r;

    // ---- prologue: tile0 -> As[0]/Bs[0]; A(1) issued to regs; B(0) drained
    LOAD_A(0);
    STG_B(0, 0, 0); STG_B(0, 0, 1); STG_B(0, 0, 2); STG_B(0, 0, 3);
    PACK_A(0);                 // compiler inserts counted vmcnt for rx here
    SCHED0();
    LOAD_A(1);
    SCHED0();
    VMCNT(8);                  // outstanding <= [B0 x4][A1 x8] -> B0 landed
    LGKM0();
    BARX();

    for (int t = 0; t < 16; ++t) {
        const int cur = t & 1, nxt = cur ^ 1;
        const int kb = (t + 1) & 15;   // B prefetch tile (wrap: dead but in-bounds)
        const int ka = (t + 2) & 15;   // A prefetch tile
        // ---- P1: Q(0,0); issue B(t+1) first half
        rd_a(As[cur], ra0, quad, a);
        rd_b<0>(Bs[cur], rb0, quad, bq);
        STG_B(nxt, kb, 0); STG_B(nxt, kb, 1);
        BARX(); LGKM0();
        PRIO1(); mmq<0, 0>(a, bq, acc); PRIO0();
        BARX();
        // ---- P2: Q(0,1); issue B(t+1) second half; pack A(t+1) -> As[nxt]
        rd_b<1>(Bs[cur], rb0, quad, bq);
        STG_B(nxt, kb, 2); STG_B(nxt, kb, 3);
        SCHED0();
        PACK_A(nxt);
        BARX(); LGKM0();
        PRIO1(); mmq<0, 1>(a, bq, acc); PRIO0();
        BARX();
        // ---- P3: Q(1,1); issue A(t+2) -> regs (pinned AFTER all B gld16)
        rd_a(As[cur], ra0 + 64, quad, a);
        SCHED0();
        LOAD_A(ka);
        SCHED0();
        BARX(); LGKM0();
        PRIO1(); mmq<1, 1>(a, bq, acc); PRIO0();
        BARX();
        // ---- P4: Q(1,0); vmcnt(8): B(t+1) landed, A(t+2) stays in flight
        VMCNT(8);
        SCHED0();
        BARX();
        PRIO1(); mmq<1, 0>(a, bq, acc); PRIO0();
        BARX();
    }
    VMCNT(0);   // drain dead wrap-prefetches before epilogue

    // epilogue: C/D layout col=lane&15, row=quad*4+reg (m89-verified)
    float bv[4];
#pragma unroll
    for (int nj = 0; nj < 4; nj++) bv[nj] = bias[n0 + wn * 64 + nj * 16 + r];
#pragma unroll
    for (int mi = 0; mi < 8; mi++)
#pragma unroll
        for (int nj = 0; nj < 4; nj++) {
            const int col = n0 + wn * 64 + nj * 16 + r;
#pragma unroll
            for (int i = 0; i < 4; i++) {
                const int row = m0 + wm * 128 + mi * 16 + quad * 4 + i;
                out[(size_t)row * N_DIM + col] = acc[mi][nj][i] + bv[nj];
            }
        }
#undef STG_B
#undef LOAD_A
#undef PACK_A
}

// ---- fallback (small ws): fused fp32->bf16 conversion GEMM, 128-tile ----
__global__ __launch_bounds__(256) void k_gemm_f32(
    const float* __restrict__ x, const ushort* __restrict__ wt,
    const float* __restrict__ bias, float* __restrict__ out) {
    __shared__ __align__(16) float  Asf[BM * BK];
    __shared__ __align__(16) ushort Bsf[BN * BK];

    const int tid  = threadIdx.x;
    const int lane = tid & 63;
    const int wv   = tid >> 6;
    const int wm   = wv >> 1;
    const int wn   = wv & 1;
    const int r    = lane & 15;
    const int quad = lane >> 4;
    int mb, nb;
    block_map(blockIdx.x, mb, nb);
    const int m0 = mb * BM;
    const int n0 = nb * BN;

    const int arow = lane >> 3;
    const int ac4  = (lane & 7) ^ arow;
    const float* gA = x + (size_t)(m0 + wv * 32 + arow) * K_DIM + ac4 * 4;
    float* lA = Asf + (wv * 32) * BK;

    const int brow = lane >> 2;
    const int bc4  = lane & 3;
    const ushort* gB = wt + (size_t)(n0 + wv * 32 + brow) * K_DIM + bc4 * 8;
    ushort* lB = Bsf + (wv * 32) * BK;

    f32x4 acc[4][4];
#pragma unroll
    for (int i = 0; i < 4; i++)
#pragma unroll
        for (int j = 0; j < 4; j++)
            acc[i][j] = (f32x4){0.f, 0.f, 0.f, 0.f};

    for (int k0 = 0; k0 < K_DIM; k0 += BK) {
#pragma unroll
        for (int i = 0; i < 4; i++)
            gld16(gA + (size_t)(i * 8) * K_DIM + k0, lA + (i * 8) * BK);
#pragma unroll
        for (int i = 0; i < 2; i++)
            gld16(gB + (size_t)(i * 16) * K_DIM + k0, lB + (i * 16) * BK);
        __syncthreads();

        short8 a[4], b[4];
#pragma unroll
        for (int nj = 0; nj < 4; nj++)
            b[nj] = *(const short8*)(Bsf + (wn * 64 + nj * 16 + r) * BK + quad * 8);
#pragma unroll
        for (int mi = 0; mi < 4; mi++) {
            const float* pa = Asf + (wm * 64 + mi * 16 + r) * BK;
            const int g0 = ((quad * 2) ^ (r & 7)) * 4;
            const int g1 = ((quad * 2 + 1) ^ (r & 7)) * 4;
            float4 f0 = *(const float4*)(pa + g0);
            float4 f1 = *(const float4*)(pa + g1);
            union { short8 v; uint32_t u[4]; } pk;
            pk.u[0] = pack2(f0.x, f0.y);
            pk.u[1] = pack2(f0.z, f0.w);
            pk.u[2] = pack2(f1.x, f1.y);
            pk.u[3] = pack2(f1.z, f1.w);
            a[mi] = pk.v;
        }
#pragma unroll
        for (int mi = 0; mi < 4; mi++)
#pragma unroll
            for (int nj = 0; nj < 4; nj++)
                acc[mi][nj] = __builtin_amdgcn_mfma_f32_16x16x32_bf16(
                    a[mi], b[nj], acc[mi][nj], 0, 0, 0);
        __syncthreads();
    }

    float bv[4];
#pragma unroll
    for (int nj = 0; nj < 4; nj++) bv[nj] = bias[n0 + wn * 64 + nj * 16 + r];
#pragma unroll
    for (int mi = 0; mi < 4; mi++)
#pragma unroll
        for (int nj = 0; nj < 4; nj++) {
            const int col = n0 + wn * 64 + nj * 16 + r;
#pragma unroll
            for (int i = 0; i < 4; i++) {
                const int row = m0 + wm * 64 + mi * 16 + quad * 4 + i;
                out[(size_t)row * N_DIM + col] = acc[mi][nj][i] + bv[nj];
            }
        }
}

extern "C" void kernel_launch(void* const* d_in, const int* in_sizes, int n_in,
                              void* d_out, int out_size, void* d_ws, size_t ws_size,
                              hipStream_t stream) {
    const float* x = (const float*)d_in[0];
    const float* W = (const float*)d_in[1];
    const float* b = (const float*)d_in[2];
    float* out = (float*)d_out;
    double* wsd = (double*)d_ws;                       // ws[0]=thr, ws[8..263]=partials
    ushort* wt = (ushort*)((char*)d_ws + 4096);        // 2 MB ternary bf16 [O,K]
    const int M = in_sizes[0] / K_DIM;                 // 32768

    const size_t WS_NEED = 4096 + (size_t)N_DIM * K_DIM * sizeof(ushort);

    const int n4 = (K_DIM * N_DIM) / 4;
    k_abs_partial<<<256, 256, 0, stream>>>(W, wsd + 8, n4);
    k_abs_final<<<1, 256, 0, stream>>>(wsd);
    k_quant<<<n4 / 256, 256, 0, stream>>>(W, wsd, wt, n4);

    if (ws_size >= WS_NEED) {
        const int nb8 = (M / TBM) * (N_DIM / TBN);     // 512, %8==0
        k_gemm_fused<<<nb8, 512, 0, stream>>>(x, wt, b, out);
    } else {
        const int nblocks = (M / BM) * (N_DIM / BN);   // 2048
        k_gemm_f32<<<nblocks, 256, 0, stream>>>(x, wt, b, out);
    }
}

// Round 4
// 289.596 us; speedup vs baseline: 1.0377x; 1.0377x over previous
//
#include <hip/hip_runtime.h>
#include <hip/hip_bf16.h>
#include <stdint.h>

#define K_DIM 1024
#define N_DIM 1024
// fallback (fused f32) tile
#define BM 128
#define BN 128
#define BK 32
// 8-phase bf16 tile
#define TBM 256
#define TBN 256
#define TBK 64

typedef __attribute__((ext_vector_type(8))) short short8;
typedef __attribute__((ext_vector_type(4))) float f32x4;

// ---- async global->LDS, 16B per lane (dest = wave-uniform base + lane*16) ----
__device__ __forceinline__ void gld16(const void* g, void* l) {
    __builtin_amdgcn_global_load_lds(
        (const __attribute__((address_space(1))) uint32_t*)(uintptr_t)g,
        (__attribute__((address_space(3))) uint32_t*)(uint32_t)(uintptr_t)l,
        16, 0, 0);
}

// pack two fp32 -> bf16x2 (round-half-up; |rel err| <= 2^-9)
__device__ __forceinline__ uint32_t pack2(float lo, float hi) {
    uint32_t a = __float_as_uint(lo) + 0x8000u;
    uint32_t b = __float_as_uint(hi) + 0x8000u;
    return __builtin_amdgcn_perm(b, a, 0x07060302u);
}

// XCD-aware swizzle for the 128-tile fallback path
__device__ __forceinline__ void block_map(int b, int& mb, int& nb) {
    int xcd = b & 7;
    int i = b >> 3;
    mb = xcd * 32 + (i >> 3);
    nb = i & 7;
}

// ---- stage 1: per-block |W| partial sums (fp64, deterministic) ----
__global__ void k_abs_partial(const float* __restrict__ W, double* __restrict__ part, int n4) {
    int stride = gridDim.x * blockDim.x;
    double s = 0.0;
    for (int i = blockIdx.x * blockDim.x + threadIdx.x; i < n4; i += stride) {
        float4 v = ((const float4*)W)[i];
        s += (double)fabsf(v.x) + (double)fabsf(v.y) + (double)fabsf(v.z) + (double)fabsf(v.w);
    }
    for (int o = 32; o > 0; o >>= 1) s += __shfl_down(s, o, 64);
    __shared__ double sm[4];
    int lane = threadIdx.x & 63, wv = threadIdx.x >> 6;
    if (lane == 0) sm[wv] = s;
    __syncthreads();
    if (threadIdx.x == 0) part[blockIdx.x] = sm[0] + sm[1] + sm[2] + sm[3];
}

// ---- stage 2: final reduce, store threshold = 0.5*mean(|W|) at ws[0] ----
__global__ void k_abs_final(double* __restrict__ ws) {
    double s = ws[8 + threadIdx.x];
    for (int o = 32; o > 0; o >>= 1) s += __shfl_down(s, o, 64);
    __shared__ double sm[4];
    int lane = threadIdx.x & 63, wv = threadIdx.x >> 6;
    if (lane == 0) sm[wv] = s;
    __syncthreads();
    if (threadIdx.x == 0)
        ws[0] = 0.5 * (sm[0] + sm[1] + sm[2] + sm[3]) / (double)(K_DIM * N_DIM);
}

// ---- stage 3: ternary quantize W -> bf16 {-1,0,+1} ----
__global__ void k_quant(const float* __restrict__ W, const double* __restrict__ thr,
                        ushort* __restrict__ wt, int n4) {
    float t = (float)thr[0];
    int i = blockIdx.x * blockDim.x + threadIdx.x;
    if (i >= n4) return;
    float4 v = ((const float4*)W)[i];
    ushort4 o;
    o.x = v.x > t ? 0x3F80u : (v.x < -t ? 0xBF80u : 0u);
    o.y = v.y > t ? 0x3F80u : (v.y < -t ? 0xBF80u : 0u);
    o.z = v.z > t ? 0x3F80u : (v.z < -t ? 0xBF80u : 0u);
    o.w = v.w > t ? 0x3F80u : (v.w < -t ? 0xBF80u : 0u);
    ((ushort4*)wt)[i] = o;
}

// ================= fused-cvt 8-phase 256x256 GEMM (v4) =====================
// A path: x fp32 -> regs rx (8x float4). Pipeline on rx:
//   P3(t-1): LOAD_A -> rx holds tile t+1
//   P3(t):   PACK_A(nxt) packs rx (tile t+1) -> As[nxt]   [BEFORE reload!]
//   P3(t):   LOAD_A(ka)  -> rx holds tile t+2
// (v3 bug: pack ran at P4, AFTER the P3 reload -> packed tile t+2 into t+1
//  slot -> absmax 207. Pack must precede the reload.)
// B path: wt bf16 via global_load_lds, pre-swizzled global source, linear dest.
// LDS tile layout: [256 rows][64 bf16], 128B/row; byte ^= ((row&7)<<4).
// Frag budget: a[4][2]=32 + b2[2][2]=16 (b-lo reloaded in P4) + rx=32 +
//              acc 128 -> ~233 of 256 cap, no spill.
// vmcnt: per iter issue order [A(t+1)x8 @P3(t-1)][B(t+1)x4 @P1/P2][A(t+2)x8 @P3]
//        -> VMCNT(8) at P4 drains B(t+1), keeps A(t+2) in flight.

__device__ __forceinline__ short8 ldfrag(const ushort* base, int row, int cb) {
    return *(const short8*)((const char*)base + (row << 7) + (cb ^ ((row & 7) << 4)));
}

__device__ __forceinline__ void rd_a(const ushort* base, int row0, int quad, short8 (&a)[4][2]) {
#pragma unroll
    for (int mi = 0; mi < 4; mi++) {
        const int row = row0 + mi * 16;
        a[mi][0] = ldfrag(base, row, (quad << 4));
        a[mi][1] = ldfrag(base, row, 64 + (quad << 4));
    }
}

__device__ __forceinline__ void rd_b2(const ushort* base, int row0, int nh, int quad,
                                      short8 (&b2)[2][2]) {
#pragma unroll
    for (int j = 0; j < 2; j++) {
        const int row = row0 + (nh * 2 + j) * 16;
        b2[j][0] = ldfrag(base, row, (quad << 4));
        b2[j][1] = ldfrag(base, row, 64 + (quad << 4));
    }
}

template <int MH, int NH>
__device__ __forceinline__ void mmq2(const short8 (&a)[4][2], const short8 (&b2)[2][2],
                                     f32x4 (&acc)[8][4]) {
#pragma unroll
    for (int mi = 0; mi < 4; mi++)
#pragma unroll
        for (int j = 0; j < 2; j++) {
            acc[MH * 4 + mi][NH * 2 + j] = __builtin_amdgcn_mfma_f32_16x16x32_bf16(
                a[mi][0], b2[j][0], acc[MH * 4 + mi][NH * 2 + j], 0, 0, 0);
            acc[MH * 4 + mi][NH * 2 + j] = __builtin_amdgcn_mfma_f32_16x16x32_bf16(
                a[mi][1], b2[j][1], acc[MH * 4 + mi][NH * 2 + j], 0, 0, 0);
        }
}

#define VMCNT(n) asm volatile("s_waitcnt vmcnt(" #n ")" ::: "memory")
#define LGKM0()  asm volatile("s_waitcnt lgkmcnt(0)" ::: "memory")
#define BARX()   __builtin_amdgcn_s_barrier()
#define PRIO1()  __builtin_amdgcn_s_setprio(1)
#define PRIO0()  __builtin_amdgcn_s_setprio(0)
#define SCHED0() __builtin_amdgcn_sched_barrier(0)

__global__ __launch_bounds__(512, 2) void k_gemm_fused(
    const float* __restrict__ x, const ushort* __restrict__ wt,
    const float* __restrict__ bias, float* __restrict__ out) {
    __shared__ __align__(16) ushort As[2][TBM * TBK];   // 2 x 32 KB
    __shared__ __align__(16) ushort Bs[2][TBN * TBK];   // 2 x 32 KB

    const int tid  = threadIdx.x;
    const int lane = tid & 63;
    const int r    = lane & 15;
    const int quad = lane >> 4;
    const int wv   = tid >> 6;
    const int wm   = wv >> 2;      // 0..1 : 128-row half
    const int wn   = wv & 3;       // 0..3 : 64-col slice

    // bijective XCD swizzle (grid % 8 == 0); n fastest so 4 same-XCD blocks share A
    const int cpx  = gridDim.x >> 3;
    const int bswz = (blockIdx.x & 7) * cpx + (blockIdx.x >> 3);
    const int m0 = (bswz >> 2) * TBM;
    const int n0 = (bswz & 3) * TBN;

    // ---- B staging (gld16): thread -> (row = tid>>3, 16B chunk = tid&7), pre-swz src
    const int srow = tid >> 3;
    const int scol = ((tid & 7) ^ (srow & 7)) << 3;
    const ushort* gB = wt + (size_t)(n0 + srow) * K_DIM + scol;
    const int ldst = srow * TBK + ((tid & 7) << 3);
#define STG_B(d, kt, u) gld16(gB + (size_t)((u) * 64) * K_DIM + (kt) * TBK, &Bs[d][(u) * 64 * TBK + ldst])

    // ---- A staging (reg): thread covers rows (tid>>4)+32s, float4 col = tid&15
    const float* gAx = x + (size_t)(m0 + (tid >> 4)) * K_DIM + (tid & 15) * 4;
    // LDS write byte offset within a row (swizzled; row&7 == (tid>>4)&7 for all s)
    const int cA = ((tid & 15) * 8) ^ (((tid >> 4) & 7) << 4);
    float4 rx[8];

#define LOAD_A(kt)                                                              \
    {                                                                           \
        _Pragma("unroll") for (int s = 0; s < 8; s++)                           \
            rx[s] = *(const float4*)(gAx + (size_t)(s * 32) * K_DIM + (kt) * TBK); \
    }
#define PACK_A(d)                                                               \
    {                                                                           \
        char* ab = (char*)As[d];                                                \
        _Pragma("unroll") for (int s = 0; s < 8; s++) {                         \
            uint2 w;                                                            \
            w.x = pack2(rx[s].x, rx[s].y);                                      \
            w.y = pack2(rx[s].z, rx[s].w);                                      \
            *(uint2*)(ab + (((tid >> 4) + 32 * s) << 7) + cA) = w;              \
        }                                                                       \
    }

    f32x4 acc[8][4];
#pragma unroll
    for (int i = 0; i < 8; i++)
#pragma unroll
        for (int j = 0; j < 4; j++) acc[i][j] = (f32x4){0.f, 0.f, 0.f, 0.f};

    short8 a[4][2], b2[2][2];
    const int ra0 = wm * 128 + r;
    const int rb0 = wn * 64 + r;

    // ---- prologue: A(0)->regs->As[0]; B(0)->Bs[0] via DMA; A(1)->regs
    LOAD_A(0);
    STG_B(0, 0, 0); STG_B(0, 0, 1); STG_B(0, 0, 2); STG_B(0, 0, 3);
    PACK_A(0);                 // auto vmcnt(4): A(0) drained, B(0) may remain
    SCHED0();
    LOAD_A(1);
    SCHED0();
    VMCNT(8);                  // outstanding <= [B0 x4][A1 x8] -> B0 landed
    LGKM0();                   // pack writes drained
    BARX();

    for (int t = 0; t < 16; ++t) {
        const int cur = t & 1, nxt = cur ^ 1;
        const int kb = (t + 1) & 15;   // B prefetch tile (wrap: dead but in-bounds)
        const int ka = (t + 2) & 15;   // A prefetch tile
        // ---- P1: Q(0,0) [a-lo x b-lo]; issue B(t+1) first half
        rd_a(As[cur], ra0, quad, a);
        rd_b2(Bs[cur], rb0, 0, quad, b2);
        STG_B(nxt, kb, 0); STG_B(nxt, kb, 1);
        BARX(); LGKM0();
        PRIO1(); mmq2<0, 0>(a, b2, acc); PRIO0();
        BARX();
        // ---- P2: Q(0,1) [a-lo x b-hi]; issue B(t+1) second half
        rd_b2(Bs[cur], rb0, 1, quad, b2);
        STG_B(nxt, kb, 2); STG_B(nxt, kb, 3);
        BARX(); LGKM0();
        PRIO1(); mmq2<0, 1>(a, b2, acc); PRIO0();
        BARX();
        // ---- P3: Q(1,1) [a-hi x b-hi];
        //      PACK rx(tile t+1) -> As[nxt]  BEFORE reloading rx with tile t+2.
        //      Pack's auto-wait is vmcnt(4) (A(t+1) old, B(t+1)x4 newer stay).
        rd_a(As[cur], ra0 + 64, quad, a);
        PACK_A(nxt);
        SCHED0();
        LOAD_A(ka);
        SCHED0();
        BARX(); LGKM0();       // drains rd_a reads + pack writes; end-BARX publishes
        PRIO1(); mmq2<1, 1>(a, b2, acc); PRIO0();
        BARX();
        // ---- P4: Q(1,0) [a-hi x b-lo reload];
        //      VMCNT(8): B(t+1) landed, A(t+2)x8 stays in flight
        rd_b2(Bs[cur], rb0, 0, quad, b2);
        VMCNT(8);
        BARX(); LGKM0();
        PRIO1(); mmq2<1, 0>(a, b2, acc); PRIO0();
        BARX();
    }
    VMCNT(0);   // drain dead wrap-prefetches before epilogue

    // epilogue: C/D layout col=lane&15, row=quad*4+reg (m89-verified)
    float bv[4];
#pragma unroll
    for (int nj = 0; nj < 4; nj++) bv[nj] = bias[n0 + wn * 64 + nj * 16 + r];
#pragma unroll
    for (int mi = 0; mi < 8; mi++)
#pragma unroll
        for (int nj = 0; nj < 4; nj++) {
            const int col = n0 + wn * 64 + nj * 16 + r;
#pragma unroll
            for (int i = 0; i < 4; i++) {
                const int row = m0 + wm * 128 + mi * 16 + quad * 4 + i;
                out[(size_t)row * N_DIM + col] = acc[mi][nj][i] + bv[nj];
            }
        }
#undef STG_B
#undef LOAD_A
#undef PACK_A
}

// ---- fallback (small ws): fused fp32->bf16 conversion GEMM, 128-tile ----
__global__ __launch_bounds__(256) void k_gemm_f32(
    const float* __restrict__ x, const ushort* __restrict__ wt,
    const float* __restrict__ bias, float* __restrict__ out) {
    __shared__ __align__(16) float  Asf[BM * BK];
    __shared__ __align__(16) ushort Bsf[BN * BK];

    const int tid  = threadIdx.x;
    const int lane = tid & 63;
    const int wv   = tid >> 6;
    const int wm   = wv >> 1;
    const int wn   = wv & 1;
    const int r    = lane & 15;
    const int quad = lane >> 4;
    int mb, nb;
    block_map(blockIdx.x, mb, nb);
    const int m0 = mb * BM;
    const int n0 = nb * BN;

    const int arow = lane >> 3;
    const int ac4  = (lane & 7) ^ arow;
    const float* gA = x + (size_t)(m0 + wv * 32 + arow) * K_DIM + ac4 * 4;
    float* lA = Asf + (wv * 32) * BK;

    const int brow = lane >> 2;
    const int bc4  = lane & 3;
    const ushort* gB = wt + (size_t)(n0 + wv * 32 + brow) * K_DIM + bc4 * 8;
    ushort* lB = Bsf + (wv * 32) * BK;

    f32x4 acc[4][4];
#pragma unroll
    for (int i = 0; i < 4; i++)
#pragma unroll
        for (int j = 0; j < 4; j++)
            acc[i][j] = (f32x4){0.f, 0.f, 0.f, 0.f};

    for (int k0 = 0; k0 < K_DIM; k0 += BK) {
#pragma unroll
        for (int i = 0; i < 4; i++)
            gld16(gA + (size_t)(i * 8) * K_DIM + k0, lA + (i * 8) * BK);
#pragma unroll
        for (int i = 0; i < 2; i++)
            gld16(gB + (size_t)(i * 16) * K_DIM + k0, lB + (i * 16) * BK);
        __syncthreads();

        short8 a[4], b[4];
#pragma unroll
        for (int nj = 0; nj < 4; nj++)
            b[nj] = *(const short8*)(Bsf + (wn * 64 + nj * 16 + r) * BK + quad * 8);
#pragma unroll
        for (int mi = 0; mi < 4; mi++) {
            const float* pa = Asf + (wm * 64 + mi * 16 + r) * BK;
            const int g0 = ((quad * 2) ^ (r & 7)) * 4;
            const int g1 = ((quad * 2 + 1) ^ (r & 7)) * 4;
            float4 f0 = *(const float4*)(pa + g0);
            float4 f1 = *(const float4*)(pa + g1);
            union { short8 v; uint32_t u[4]; } pk;
            pk.u[0] = pack2(f0.x, f0.y);
            pk.u[1] = pack2(f0.z, f0.w);
            pk.u[2] = pack2(f1.x, f1.y);
            pk.u[3] = pack2(f1.z, f1.w);
            a[mi] = pk.v;
        }
#pragma unroll
        for (int mi = 0; mi < 4; mi++)
#pragma unroll
            for (int nj = 0; nj < 4; nj++)
                acc[mi][nj] = __builtin_amdgcn_mfma_f32_16x16x32_bf16(
                    a[mi], b[nj], acc[mi][nj], 0, 0, 0);
        __syncthreads();
    }

    float bv[4];
#pragma unroll
    for (int nj = 0; nj < 4; nj++) bv[nj] = bias[n0 + wn * 64 + nj * 16 + r];
#pragma unroll
    for (int mi = 0; mi < 4; mi++)
#pragma unroll
        for (int nj = 0; nj < 4; nj++) {
            const int col = n0 + wn * 64 + nj * 16 + r;
#pragma unroll
            for (int i = 0; i < 4; i++) {
                const int row = m0 + wm * 64 + mi * 16 + quad * 4 + i;
                out[(size_t)row * N_DIM + col] = acc[mi][nj][i] + bv[nj];
            }
        }
}

extern "C" void kernel_launch(void* const* d_in, const int* in_sizes, int n_in,
                              void* d_out, int out_size, void* d_ws, size_t ws_size,
                              hipStream_t stream) {
    const float* x = (const float*)d_in[0];
    const float* W = (const float*)d_in[1];
    const float* b = (const float*)d_in[2];
    float* out = (float*)d_out;
    double* wsd = (double*)d_ws;                       // ws[0]=thr, ws[8..263]=partials
    ushort* wt = (ushort*)((char*)d_ws + 4096);        // 2 MB ternary bf16 [O,K]
    const int M = in_sizes[0] / K_DIM;                 // 32768

    const size_t WS_NEED = 4096 + (size_t)N_DIM * K_DIM * sizeof(ushort);

    const int n4 = (K_DIM * N_DIM) / 4;
    k_abs_partial<<<256, 256, 0, stream>>>(W, wsd + 8, n4);
    k_abs_final<<<1, 256, 0, stream>>>(wsd);
    k_quant<<<n4 / 256, 256, 0, stream>>>(W, wsd, wt, n4);

    if (ws_size >= WS_NEED) {
        const int nb8 = (M / TBM) * (N_DIM / TBN);     // 512, %8==0
        k_gemm_fused<<<nb8, 512, 0, stream>>>(x, wt, b, out);
    } else {
        const int nblocks = (M / BM) * (N_DIM / BN);   // 2048
        k_gemm_f32<<<nblocks, 256, 0, stream>>>(x, wt, b, out);
    }
}